// Round 1
// 262.071 us; speedup vs baseline: 1.0190x; 1.0190x over previous
//
#include <hip/hip_runtime.h>
#include <hip/hip_bf16.h>

#define NTOK 49
#define NPAD 64
#define CDIM 128
#define C3   384
#define NHEAD 4
#define HDIM 32
#define SCALE 0.17677669529663687f

#define QS 136   // q/k/x row stride (elems): 272 B rows, bank offset 4 mod 32
#define VS 72    // vT row stride (144 B, 16B-aligned)
#define PS 72    // per-wave P row stride

typedef __attribute__((ext_vector_type(8))) __bf16 bf16x8;
typedef __attribute__((ext_vector_type(4))) __bf16 bf16x4;
typedef __attribute__((ext_vector_type(4))) float f32x4;

#define PIN(v) asm volatile("" : "+v"(v))   // block load-rematerialization / sinking

// ws layout (bytes):
//   qkvT  __bf16[384][128]  @ 0        (98304 B)  qkvT[n][k] = qkv_w[k][n]; q rows pre-scaled
//   projT __bf16[128][128]  @ 98304    (32768 B)
//   blut  float [4][64][64] @ 131072   (65536 B)  rel-bias LUT [h][q][k], k>=49 -> -1e30

__global__ __launch_bounds__(256) void prep_kernel(
    const float* __restrict__ qkv_w, const float* __restrict__ proj_w,
    const float* __restrict__ bias_table,
    __bf16* __restrict__ qkvT, __bf16* __restrict__ projT, float* __restrict__ blut)
{
  int o = blockIdx.x * 256 + threadIdx.x;
  if (o < CDIM * C3) {
    // linear over qkv_w: coalesced read, scattered bf16 write (L2 absorbs 98KB)
    int k = o / C3, n = o - k * C3;
    float v = qkv_w[o];
    if (n < CDIM) v *= SCALE;              // fold softmax scale into q weights
    qkvT[n * CDIM + k] = (__bf16)v;
  } else if (o < CDIM * C3 + CDIM * CDIM) {
    int o2 = o - CDIM * C3;
    int k = o2 >> 7, n = o2 & 127;
    projT[n * CDIM + k] = (__bf16)proj_w[o2];
  } else if (o < CDIM * C3 + CDIM * CDIM + NHEAD * NPAD * NPAD) {
    int t3 = o - (CDIM * C3 + CDIM * CDIM);
    int hh = t3 >> 12, r = (t3 >> 6) & 63, c = t3 & 63;
    float v;
    if (c >= NTOK) v = -1e30f;             // softmax mask for padded key columns
    else if (r >= NTOK) v = 0.0f;          // padded query rows: finite, never stored
    else {
      int idx = (r / 7 - c / 7 + 6) * 13 + (r % 7 - c % 7 + 6);
      v = bias_table[idx * NHEAD + hh];
    }
    blut[t3] = v;
  }
}

// 512 threads = 8 waves. LDS 53248 B -> 3 blocks/CU -> 24 waves/CU (6/SIMD).
__global__ __launch_bounds__(512, 6) void attn_kernel(
    const float* __restrict__ x, const float* __restrict__ qkv_b,
    const float* __restrict__ proj_b,
    const __bf16* __restrict__ qkvT, const __bf16* __restrict__ projT,
    const float* __restrict__ blut, float* __restrict__ out)
{
  __shared__ __align__(16) char smem[53248];
  __bf16* qs_ = (__bf16*)smem;            // phase 0/1: staged x A-tile; then q; then O overlay
  __bf16* ks_ = qs_ + NPAD * QS;          // 17408 B
  __bf16* vT_ = ks_ + NPAD * QS;          // 18432 B; after bv-fragment loads: P tiles
  __bf16* xa_ = qs_;
  __bf16* Pm_ = vT_;
  __bf16* O_  = qs_;

  const int tid  = threadIdx.x;
  const int wave = tid >> 6;              // 0..7
  const int lane = tid & 63;
  const int l15  = lane & 15;
  const int lg   = lane >> 4;

  const int win = blockIdx.x;
  const int b  = win >> 6;
  const int wh = (win >> 3) & 7;
  const int ww = win & 7;
  const float* xbase = x + (((b * 56) + wh * 7) * 56 + ww * 7) * CDIM;

  // ---- phase 0: stage x window into LDS as bf16 A-tile (rows 49..63 zeroed) ----
  #pragma unroll
  for (int p = 0; p < 2; ++p) {
    int L = p * 512 + tid;
    int r = L >> 4, c = L & 15;
    bf16x8 v8;
    if (r < NTOK) {
      const float* g = xbase + ((r / 7) * 56 + (r % 7)) * CDIM + c * 8;
      f32x4 x0 = *(const f32x4*)g;
      f32x4 x1 = *(const f32x4*)(g + 4);
      v8[0] = (__bf16)x0[0]; v8[1] = (__bf16)x0[1]; v8[2] = (__bf16)x0[2]; v8[3] = (__bf16)x0[3];
      v8[4] = (__bf16)x1[0]; v8[5] = (__bf16)x1[1]; v8[6] = (__bf16)x1[2]; v8[7] = (__bf16)x1[3];
    } else {
      #pragma unroll
      for (int q2 = 0; q2 < 8; ++q2) v8[q2] = (__bf16)0.0f;
    }
    *(bf16x8*)(xa_ + r * QS + c * 8) = v8;
  }

  // ---- per-wave channel tile: wave w owns channels w*16..w*16+15 of each of q/k/v ----
  const int nch = wave * 16 + l15;
  bf16x8 bwk[4], bwv[4];
  #pragma unroll
  for (int kt = 0; kt < 4; ++kt) {
    bwk[kt] = *(const bf16x8*)(qkvT + (CDIM + nch) * CDIM + kt * 32 + lg * 8);     PIN(bwk[kt]);
    bwv[kt] = *(const bf16x8*)(qkvT + (2 * CDIM + nch) * CDIM + kt * 32 + lg * 8); PIN(bwv[kt]);
  }
  const float kb = qkv_b[CDIM + nch];
  const float vb = qkv_b[2 * CDIM + nch];

  __syncthreads();   // [1] x tile ready

  // ---- pass 1: k and v GEMM (written to LDS immediately) ----
  #pragma unroll 2
  for (int mt = 0; mt < 4; ++mt) {
    bf16x8 a[4];
    #pragma unroll
    for (int kt = 0; kt < 4; ++kt)
      a[kt] = *(const bf16x8*)(xa_ + (mt * 16 + l15) * QS + kt * 32 + lg * 8);
    f32x4 ck, cv;
    ck[0]=0.f; ck[1]=0.f; ck[2]=0.f; ck[3]=0.f;
    cv[0]=0.f; cv[1]=0.f; cv[2]=0.f; cv[3]=0.f;
    #pragma unroll
    for (int kt = 0; kt < 4; ++kt) {
      ck = __builtin_amdgcn_mfma_f32_16x16x32_bf16(a[kt], bwk[kt], ck, 0, 0, 0);
      cv = __builtin_amdgcn_mfma_f32_16x16x32_bf16(a[kt], bwv[kt], cv, 0, 0, 0);
    }
    const int r0 = mt * 16 + lg * 4;
    #pragma unroll
    for (int i = 0; i < 4; ++i)
      ks_[(r0 + i) * QS + nch] = (__bf16)(ck[i] + kb);
    bf16x4 vv;
    #pragma unroll
    for (int i = 0; i < 4; ++i) vv[i] = (__bf16)(cv[i] + vb);
    *(bf16x4*)(vT_ + nch * VS + r0) = vv;   // vT[ch][token]
  }

  // ---- pass 2: q GEMM, accumulators deferred in registers (x tile still live) ----
  bf16x8 bwq[4];
  #pragma unroll
  for (int kt = 0; kt < 4; ++kt) {
    bwq[kt] = *(const bf16x8*)(qkvT + nch * CDIM + kt * 32 + lg * 8); PIN(bwq[kt]);
  }
  const float qb = qkv_b[nch] * SCALE;     // match pre-scaled q weights
  f32x4 aq[4];
  #pragma unroll
  for (int mt = 0; mt < 4; ++mt) {
    bf16x8 a[4];
    #pragma unroll
    for (int kt = 0; kt < 4; ++kt)
      a[kt] = *(const bf16x8*)(xa_ + (mt * 16 + l15) * QS + kt * 32 + lg * 8);
    aq[mt][0]=0.f; aq[mt][1]=0.f; aq[mt][2]=0.f; aq[mt][3]=0.f;
    #pragma unroll
    for (int kt = 0; kt < 4; ++kt)
      aq[mt] = __builtin_amdgcn_mfma_f32_16x16x32_bf16(a[kt], bwq[kt], aq[mt], 0, 0, 0);
  }

  __syncthreads();   // [2] all x-tile reads complete; k/v tiles ready

  // ---- prefetch attention operands (ks/vT reads; disjoint from q writes below) ----
  const int h  = wave & 3;
  const int hc = h * HDIM;
  bf16x8 akf[4];                           // K as A-fragments (S^T = K * Q^T)
  #pragma unroll
  for (int nt = 0; nt < 4; ++nt)
    akf[nt] = *(const bf16x8*)(ks_ + (nt * 16 + l15) * QS + hc + lg * 8);
  bf16x8 bv[2][2];                         // V^T as B-fragments for PV
  #pragma unroll
  for (int n16 = 0; n16 < 2; ++n16)
    #pragma unroll
    for (int kt = 0; kt < 2; ++kt)
      bv[n16][kt] = *(const bf16x8*)(vT_ + (hc + n16 * 16 + l15) * VS + kt * 32 + lg * 8);

  // ---- store deferred q over the dead x tile ----
  #pragma unroll
  for (int mt = 0; mt < 4; ++mt) {
    const int r0 = mt * 16 + lg * 4;
    #pragma unroll
    for (int i = 0; i < 4; ++i)
      qs_[(r0 + i) * QS + nch] = (__bf16)(aq[mt][i] + qb);
  }

  __syncthreads();   // [3] q ready; vT fully consumed into regs -> region becomes P

  // ---- phase 2: attention. wave = (head = wave&3, M-half = wave>>2) ----
  const float* blh = blut + h * 4096;
  __bf16* Pw = Pm_ + wave * 16 * PS;

  #pragma unroll
  for (int mi = 0; mi < 2; ++mi) {
    const int m0 = ((wave >> 2) * 2 + mi) * 16;

    f32x4 bias[4];                         // bias[q=m0+l15][k=nt*16+lg*4+i], vectorized
    #pragma unroll
    for (int nt = 0; nt < 4; ++nt)
      bias[nt] = *(const f32x4*)(blh + (m0 + l15) * 64 + nt * 16 + lg * 4);

    bf16x8 qf = *(const bf16x8*)(qs_ + (m0 + l15) * QS + hc + lg * 8);  // Q^T B-frag
    f32x4 s[4];                            // S^T: row k = nt*16+lg*4+i, col q = m0+l15
    #pragma unroll
    for (int nt = 0; nt < 4; ++nt) {
      f32x4 z; z[0]=0.f; z[1]=0.f; z[2]=0.f; z[3]=0.f;
      s[nt] = __builtin_amdgcn_mfma_f32_16x16x32_bf16(akf[nt], qf, z, 0, 0, 0);
    }

    // softmax, no max-subtraction (|s|<~8 << 88); store raw exp, 1/sum deferred to O
    float es[4][4];
    float p0 = 0.f, p1 = 0.f;
    #pragma unroll
    for (int nt = 0; nt < 4; ++nt) {
      #pragma unroll
      for (int i = 0; i < 4; ++i) {
        float e = __expf(s[nt][i] + bias[nt][i]);
        es[nt][i] = e;
        if (nt & 1) p1 += e; else p0 += e;
      }
      bf16x4 pv;
      #pragma unroll
      for (int i = 0; i < 4; ++i) pv[i] = (__bf16)es[nt][i];
      *(bf16x4*)(Pw + l15 * PS + nt * 16 + lg * 4) = pv;   // P[q_local=l15][k]
    }
    float psum = p0 + p1;                  // per-lane partial over its 16 k's
    psum += __shfl_xor(psum, 16);          // combine across lg groups (same q column)
    psum += __shfl_xor(psum, 32);
    const float inv = __builtin_amdgcn_rcpf(psum);

    f32x4 o0, o1;
    o0[0]=0.f;o0[1]=0.f;o0[2]=0.f;o0[3]=0.f; o1[0]=0.f;o1[1]=0.f;o1[2]=0.f;o1[3]=0.f;
    #pragma unroll
    for (int kt = 0; kt < 2; ++kt) {
      bf16x8 ap = *(const bf16x8*)(Pw + l15 * PS + kt * 32 + lg * 8);
      o0 = __builtin_amdgcn_mfma_f32_16x16x32_bf16(ap, bv[0][kt], o0, 0, 0, 0);
      o1 = __builtin_amdgcn_mfma_f32_16x16x32_bf16(ap, bv[1][kt], o1, 0, 0, 0);
    }
    float invr[4];                         // redistribute inv: O rows are lg*4+i
    #pragma unroll
    for (int i = 0; i < 4; ++i) invr[i] = __shfl(inv, lg * 4 + i);
    const int r0 = m0 + lg * 4;
    #pragma unroll
    for (int i = 0; i < 4; ++i) {
      O_[(r0 + i) * QS + hc +      l15] = (__bf16)(o0[i] * invr[i]);
      O_[(r0 + i) * QS + hc + 16 + l15] = (__bf16)(o1[i] * invr[i]);
    }
  }

  // ---- prefetch proj weights: latency hides under barrier + stragglers ----
  const int nb2 = wave * 16;
  bf16x8 bp[4];
  #pragma unroll
  for (int kt = 0; kt < 4; ++kt) {
    bp[kt] = *(const bf16x8*)(projT + (nb2 + l15) * CDIM + kt * 32 + lg * 8);
    PIN(bp[kt]);
  }
  const float pb = proj_b[nb2 + l15];

  __syncthreads();   // [4] O ready across waves

  // ---- phase 3: proj GEMM, wave owns 16 output cols ----
  float* outw = out + (((b * 56) + wh * 7) * 56 + ww * 7) * CDIM;
  #pragma unroll
  for (int mt = 0; mt < 4; ++mt) {
    bf16x8 ao[4];
    #pragma unroll
    for (int kt = 0; kt < 4; ++kt)
      ao[kt] = *(const bf16x8*)(O_ + (mt * 16 + l15) * QS + kt * 32 + lg * 8);
    f32x4 c0;
    c0[0]=0.f;c0[1]=0.f;c0[2]=0.f;c0[3]=0.f;
    #pragma unroll
    for (int kt = 0; kt < 4; ++kt)
      c0 = __builtin_amdgcn_mfma_f32_16x16x32_bf16(ao[kt], bp[kt], c0, 0, 0, 0);
    #pragma unroll
    for (int i = 0; i < 4; ++i) {
      const int r = mt * 16 + lg * 4 + i;
      if (r < NTOK) {
        float* po = outw + ((r / 7) * 56 + (r % 7)) * CDIM + nb2;
        po[l15] = c0[i] + pb;
      }
    }
  }
}

extern "C" void kernel_launch(void* const* d_in, const int* in_sizes, int n_in,
                              void* d_out, int out_size, void* d_ws, size_t ws_size,
                              hipStream_t stream) {
  const float* x          = (const float*)d_in[0];
  const float* qkv_w      = (const float*)d_in[1];
  const float* qkv_b      = (const float*)d_in[2];
  const float* proj_w     = (const float*)d_in[3];
  const float* proj_b     = (const float*)d_in[4];
  const float* bias_table = (const float*)d_in[5];

  __bf16* qkvT  = (__bf16*)d_ws;
  __bf16* projT = qkvT + C3 * CDIM;
  float*  blut  = (float*)((char*)d_ws + 131072);
  float*  out   = (float*)d_out;

  hipLaunchKernelGGL(prep_kernel, dim3(320), dim3(256), 0, stream,
                     qkv_w, proj_w, bias_table, qkvT, projT, blut);
  hipLaunchKernelGGL(attn_kernel, dim3(4096), dim3(512), 0, stream,
                     x, qkv_b, proj_b, qkvT, projT, blut, out);
}